// Round 16
// baseline (231.285 us; speedup 1.0000x reference)
//
#include <hip/hip_runtime.h>
#include <cstdint>

typedef unsigned short u16;
typedef short bf16x8_t __attribute__((ext_vector_type(8)));
typedef float f32x4_t __attribute__((ext_vector_type(4)));

#define DEVFN __device__ __forceinline__

DEVFN u16 f2bf(float f) {
  unsigned u = __builtin_bit_cast(unsigned, f);
  u = (u + 0x7fffu + ((u >> 16) & 1u)) >> 16;
  return (u16)u;
}
DEVFN float bf2f(u16 s) {
  unsigned u = ((unsigned)s) << 16;
  return __builtin_bit_cast(float, u);
}
DEVFN unsigned pk2bf(float a, float b) {
  return (unsigned)f2bf(a) | ((unsigned)f2bf(b) << 16);
}

// global -> LDS direct copy, 16B per lane; LDS dest linear in lane order.
DEVFN void gload_lds16(const u16* g, u16* l) {
  __builtin_amdgcn_global_load_lds(
      (const __attribute__((address_space(1))) void*)g,
      (__attribute__((address_space(3))) void*)l, 16, 0, 0);
}

// ---------------- prep: W1/W2 transpose->bf16, deg histogram ----------------
__global__ void prep_kernel(const float* __restrict__ W1, const float* __restrict__ W2,
                            const int* __restrict__ edst,
                            u16* __restrict__ w1t, u16* __restrict__ w2t,
                            int* __restrict__ cnt, int e) {
  int b = blockIdx.x;
  if (b < 512) {                         // W1 [256][512] -> w1t [512][256]
    int idx = b * 256 + threadIdx.x;
    int k = idx >> 9, m = idx & 511;
    w1t[m * 256 + k] = f2bf(W1[idx]);
  } else if (b < 640) {                  // W2 [512][64] -> w2t [64][512]
    int idx = (b - 512) * 256 + threadIdx.x;
    int k = idx >> 6, m = idx & 63;
    w2t[m * 512 + k] = f2bf(W2[idx]);
  } else {                               // deg histogram
    int i = (b - 640) * 256 + threadIdx.x;
    if (i < e) atomicAdd(&cnt[edst[i]], 1);
  }
}

// ================= GEMM1: f32 A fused convert, PIPELINED, XCD-grouped =========
// A[M][K] f32 @ BT[NP*BN][K] bf16 -> C[M][NP*BN] bf16 + fused alpha dots.
// Pipeline (R13 structure, first time on the f32-A path): A(k+1)->f32 regs and
// B(k+1)->sB[alt] via gload_lds are issued AFTER the staging barrier, overlap
// with compute(k), and are drained by the compute-end barrier. sA single-buffered
// (rewritten only after the compute-end barrier).
// T2 swizzle (BK=64, 128B rows): slot' = slot ^ (row&7); read col ^= (rsel&7)*8.
template<int BM, int BN, int WROWS, int K, int BK, int NP, int H, int DH>
__global__ __launch_bounds__(256) void gemm1_alpha_kernel(
    const float* __restrict__ A, const u16* __restrict__ BT, u16* __restrict__ C,
    const float* __restrict__ a_s, const float* __restrict__ a_d,
    float* __restrict__ as_out, float* __restrict__ ad_out, int M)
{
  constexpr int N = NP * BN;
  constexpr int WM = BM / WROWS;
  constexpr int MF = WM / 16;
  constexpr int NF = BN / 16;
  constexpr int KK = BK / 32;
  constexpr int NSTEP = K / BK;
  static_assert(BK == 64, "swizzle derived for 128B rows");
  __shared__ __align__(16) u16 sA[BM][BK];
  __shared__ __align__(16) u16 sB[2][BN][BK];

  const int tid = threadIdx.x;
  const int lane = tid & 63;
  const int wr = tid >> 6;

  const int bid = blockIdx.x;
  const int xcd = bid & 7;
  const int rest = bid >> 3;
  const int p = rest & (NP - 1);
  const int rb = rest / NP;
  const int r = rb * 8 + xcd;
  const int NRB = (M + BM - 1) / BM;
  if (r >= NRB) return;
  const int brow = r * BM;
  const int bcol = p * BN;

  f32x4_t acc[MF][NF];
#pragma unroll
  for (int i = 0; i < MF; ++i)
#pragma unroll
    for (int j = 0; j < NF; ++j) acc[i][j] = f32x4_t{0.f, 0.f, 0.f, 0.f};

  const int rsel = lane & 15;
  const int kgrp = (lane >> 4) * 8;
  const int rx = (rsel & 7) * 8;       // read-side XOR (u16 units)

  constexpr int RA = BM * BK / 2048;   // 4 rounds
  constexpr int RBn = BN * BK / 2048;  // 4 rounds
  float4 av0[RA], av1[RA];

  // prologue: A(0) -> f32 regs, B(0) -> sB[0]
#pragma unroll
  for (int c = 0; c < RA; ++c) {
    int t = c * 256 + tid;
    int row = t >> 3;
    int gr = brow + row; gr = gr < M ? gr : M - 1;
    const float* src = A + (size_t)gr * K + (t & 7) * 8;
    av0[c] = *reinterpret_cast<const float4*>(src);
    av1[c] = *reinterpret_cast<const float4*>(src + 4);
  }
#pragma unroll
  for (int c = 0; c < RBn; ++c) {
    int t = c * 256 + tid;
    int row = t >> 3;
    int col = ((t & 7) ^ (row & 7)) * 8;
    gload_lds16(BT + (size_t)(bcol + row) * K + col, &sB[0][0][0] + t * 8);
  }

#pragma unroll
  for (int k = 0; k < NSTEP; ++k) {
    // pack + swizzled ds_write current A regs
#pragma unroll
    for (int c = 0; c < RA; ++c) {
      int t = c * 256 + tid;
      int row = t >> 3;
      uint4 pk;
      pk.x = pk2bf(av0[c].x, av0[c].y);
      pk.y = pk2bf(av0[c].z, av0[c].w);
      pk.z = pk2bf(av1[c].x, av1[c].y);
      pk.w = pk2bf(av1[c].z, av1[c].w);
      int slot = (t & 7) ^ (row & 7);
      *reinterpret_cast<uint4*>(&sA[0][0] + row * BK + slot * 8) = pk;
    }
    __syncthreads();   // sA written, sB[k&1] gloads drained
    if (k + 1 < NSTEP) {
      const int k0n = (k + 1) * BK;
#pragma unroll
      for (int c = 0; c < RA; ++c) {
        int t = c * 256 + tid;
        int row = t >> 3;
        int gr = brow + row; gr = gr < M ? gr : M - 1;
        const float* src = A + (size_t)gr * K + k0n + (t & 7) * 8;
        av0[c] = *reinterpret_cast<const float4*>(src);
        av1[c] = *reinterpret_cast<const float4*>(src + 4);
      }
#pragma unroll
      for (int c = 0; c < RBn; ++c) {
        int t = c * 256 + tid;
        int row = t >> 3;
        int col = ((t & 7) ^ (row & 7)) * 8;
        gload_lds16(BT + (size_t)(bcol + row) * K + k0n + col, &sB[(k + 1) & 1][0][0] + t * 8);
      }
    }
#pragma unroll
    for (int kk = 0; kk < KK; ++kk) {
      const int cswz = (kk * 32 + kgrp) ^ rx;
      bf16x8_t af[MF], bfr[NF];
#pragma unroll
      for (int i = 0; i < MF; ++i) {
        int row = wr * WM + i * 16 + rsel;
        af[i] = *reinterpret_cast<const bf16x8_t*>(&sA[0][0] + row * BK + cswz);
      }
#pragma unroll
      for (int j = 0; j < NF; ++j) {
        int row = j * 16 + rsel;
        bfr[j] = *reinterpret_cast<const bf16x8_t*>(&sB[k & 1][0][0] + row * BK + cswz);
      }
#pragma unroll
      for (int i = 0; i < MF; ++i)
#pragma unroll
        for (int j = 0; j < NF; ++j)
          acc[i][j] = __builtin_amdgcn_mfma_f32_16x16x32_bf16(af[i], bfr[j], acc[i][j], 0, 0, 0);
    }
    __syncthreads();   // drains k+1 prefetch; frees sA for next ds_write
  }

  const int crow0 = (lane >> 4) * 4;
  const int ccol = lane & 15;

  // C write
#pragma unroll
  for (int i = 0; i < MF; ++i)
#pragma unroll
    for (int j = 0; j < NF; ++j)
#pragma unroll
      for (int rr = 0; rr < 4; ++rr) {
        int gr = brow + wr * WM + i * 16 + crow0 + rr;
        int gc = bcol + j * 16 + ccol;
        if (gr < M) C[(size_t)gr * N + gc] = f2bf(acc[i][j][rr]);
      }

  // fused alpha dots (1 wave owns a row; BN==DH so one block owns (row, head))
  const int head = bcol / DH;
  float asv[NF], adv[NF];
#pragma unroll
  for (int j = 0; j < NF; ++j) {
    int gc = bcol + j * 16 + ccol;
    asv[j] = a_s[gc];
    adv[j] = a_d[gc];
  }
#pragma unroll
  for (int i = 0; i < MF; ++i) {
#pragma unroll
    for (int rr = 0; rr < 4; ++rr) {
      float ps = 0.f, pd = 0.f;
#pragma unroll
      for (int j = 0; j < NF; ++j) {
        float v = acc[i][j][rr];
        ps = fmaf(v, asv[j], ps);
        pd = fmaf(v, adv[j], pd);
      }
#pragma unroll
      for (int d = 1; d < 16; d <<= 1) {
        ps += __shfl_xor(ps, d, 64);
        pd += __shfl_xor(pd, d, 64);
      }
      if ((lane & 15) == 0) {
        int gr = brow + wr * WM + i * 16 + crow0 + rr;
        if (gr < M) {
          as_out[(size_t)gr * H + head] = ps;
          ad_out[(size_t)gr * H + head] = pd;
        }
      }
    }
  }
}

// ---------------- GEMM2 (swizzled gload_lds, BK=64) + fused alpha2 dots -------
template<int BM, int BN, int WROWS, int K, int BK, int H, int DH>
__global__ __launch_bounds__(256) void gemm_alpha_kernel(
    const u16* __restrict__ A, const u16* __restrict__ BT, u16* __restrict__ C,
    const float* __restrict__ a_s, const float* __restrict__ a_d,
    float* __restrict__ as_out, float* __restrict__ ad_out, int M, int N)
{
  static_assert(BN == DH, "alpha store ownership");
  static_assert(BK == 64, "swizzle derived for 128B rows");
  constexpr int WM = BM / WROWS;
  constexpr int MF = WM / 16;
  constexpr int NF = BN / 16;
  constexpr int KK = BK / 32;
  __shared__ __align__(16) u16 sA[BM][BK];
  __shared__ __align__(16) u16 sB[BN][BK];

  const int tid = threadIdx.x;
  const int lane = tid & 63;
  const int wr = tid >> 6;
  const int brow = blockIdx.x * BM;
  const int bcol = blockIdx.y * BN;

  f32x4_t acc[MF][NF];
#pragma unroll
  for (int i = 0; i < MF; ++i)
#pragma unroll
    for (int j = 0; j < NF; ++j) acc[i][j] = f32x4_t{0.f, 0.f, 0.f, 0.f};

  const int rsel = lane & 15;
  const int kgrp = (lane >> 4) * 8;
  const int rx = (rsel & 7) * 8;

#pragma unroll
  for (int k0 = 0; k0 < K; k0 += BK) {
    constexpr int RA = BM * BK / 2048;
#pragma unroll
    for (int c = 0; c < RA; ++c) {
      int t = c * 256 + tid;
      int row = t >> 3;
      int col = ((t & 7) ^ (row & 7)) * 8;
      int gr = brow + row; gr = gr < M ? gr : M - 1;
      gload_lds16(A + (size_t)gr * K + k0 + col, &sA[0][0] + t * 8);
    }
    constexpr int RB = BN * BK / 2048;
#pragma unroll
    for (int c = 0; c < RB; ++c) {
      int t = c * 256 + tid;
      int row = t >> 3;
      int col = ((t & 7) ^ (row & 7)) * 8;
      gload_lds16(BT + (size_t)(bcol + row) * K + k0 + col, &sB[0][0] + t * 8);
    }
    __syncthreads();
#pragma unroll
    for (int kk = 0; kk < KK; ++kk) {
      const int cswz = (kk * 32 + kgrp) ^ rx;
      bf16x8_t af[MF], bfr[NF];
#pragma unroll
      for (int i = 0; i < MF; ++i) {
        int row = wr * WM + i * 16 + rsel;
        af[i] = *reinterpret_cast<const bf16x8_t*>(&sA[0][0] + row * BK + cswz);
      }
#pragma unroll
      for (int j = 0; j < NF; ++j) {
        int row = j * 16 + rsel;
        bfr[j] = *reinterpret_cast<const bf16x8_t*>(&sB[0][0] + row * BK + cswz);
      }
#pragma unroll
      for (int i = 0; i < MF; ++i)
#pragma unroll
        for (int j = 0; j < NF; ++j)
          acc[i][j] = __builtin_amdgcn_mfma_f32_16x16x32_bf16(af[i], bfr[j], acc[i][j], 0, 0, 0);
    }
    __syncthreads();
  }

  const int crow0 = (lane >> 4) * 4;
  const int ccol = lane & 15;

#pragma unroll
  for (int i = 0; i < MF; ++i)
#pragma unroll
    for (int j = 0; j < NF; ++j)
#pragma unroll
      for (int rr = 0; rr < 4; ++rr) {
        int gr = brow + wr * WM + i * 16 + crow0 + rr;
        int gc = bcol + j * 16 + ccol;
        if (gr < M) C[(size_t)gr * N + gc] = f2bf(acc[i][j][rr]);
      }

  const int head = bcol / DH;
  float asv[NF], adv[NF];
#pragma unroll
  for (int j = 0; j < NF; ++j) {
    int gc = bcol + j * 16 + ccol;
    asv[j] = a_s[gc];
    adv[j] = a_d[gc];
  }
#pragma unroll
  for (int i = 0; i < MF; ++i) {
#pragma unroll
    for (int rr = 0; rr < 4; ++rr) {
      float ps = 0.f, pd = 0.f;
#pragma unroll
      for (int j = 0; j < NF; ++j) {
        float v = acc[i][j][rr];
        ps = fmaf(v, asv[j], ps);
        pd = fmaf(v, adv[j], pd);
      }
#pragma unroll
      for (int d = 1; d < 16; d <<= 1) {
        ps += __shfl_xor(ps, d, 64);
        pd += __shfl_xor(pd, d, 64);
      }
      if ((lane & 15) == 0) {
        int gr = brow + wr * WM + i * 16 + crow0 + rr;
        if (gr < M) {
          as_out[(size_t)gr * H + head] = ps;
          ad_out[(size_t)gr * H + head] = pd;
        }
      }
    }
  }
}

// ---------------- CSR build ----------------
DEVFN int block_scan_256(int v, int tid, int* wsum) {
#pragma unroll
  for (int d = 1; d < 64; d <<= 1) {
    int u = __shfl_up(v, d, 64);
    if ((tid & 63) >= d) v += u;
  }
  if ((tid & 63) == 63) wsum[tid >> 6] = v;
  __syncthreads();
  int add = 0;
#pragma unroll
  for (int w = 0; w < 4; ++w) add += (w < (tid >> 6)) ? wsum[w] : 0;
  __syncthreads();
  return v + add;
}

__global__ __launch_bounds__(256) void scan_a_kernel(const int* __restrict__ cnt, int* __restrict__ bsum, int n) {
  __shared__ int ws4[4];
  int i = blockIdx.x * 256 + threadIdx.x;
  int v = (i < n) ? cnt[i] + 1 : 0;   // +1 self loop
  int incl = block_scan_256(v, threadIdx.x, ws4);
  if (threadIdx.x == 255) bsum[blockIdx.x] = incl;
}

__global__ __launch_bounds__(256) void scan_c_kernel(
    const int* __restrict__ cnt, const int* __restrict__ bsum,
    int* __restrict__ rowoff, int* __restrict__ cursor, int n)
{
  __shared__ int ws4[4];
  __shared__ int ws4b[4];
  __shared__ int base_sh;
  int pre = 0;
  for (int w = threadIdx.x; w < blockIdx.x; w += 256) pre += bsum[w];
#pragma unroll
  for (int d = 1; d < 64; d <<= 1) pre += __shfl_xor(pre, d, 64);
  if ((threadIdx.x & 63) == 0) ws4b[threadIdx.x >> 6] = pre;
  __syncthreads();
  if (threadIdx.x == 0) base_sh = ws4b[0] + ws4b[1] + ws4b[2] + ws4b[3];
  int i = blockIdx.x * 256 + threadIdx.x;
  int v = (i < n) ? cnt[i] + 1 : 0;
  int incl = block_scan_256(v, threadIdx.x, ws4);
  int off = base_sh + incl - v;
  if (i < n) {
    rowoff[i] = off;
    cursor[i] = off;
    if (i == n - 1) rowoff[n] = off + v;
  }
}

__global__ void scatter_kernel(const int* __restrict__ srcs, const int* __restrict__ dsts,
                               int* __restrict__ cursor, int* __restrict__ csr, int e, int n) {
  int i = blockIdx.x * 256 + threadIdx.x;
  if (i >= e + n) return;
  int s, d;
  if (i < e) { s = srcs[i]; d = dsts[i]; }
  else       { s = i - e; d = s; }
  int pos = atomicAdd(&cursor[d], 1);
  csr[pos] = s;
}

// ---------------- agg1: gather h1b, fused softmax (no-max-shift), b1+ELU -------
__global__ __launch_bounds__(256) void agg1_kernel(
    const u16* __restrict__ h1, const float* __restrict__ as1,
    const float* __restrict__ ad1, const int* __restrict__ rowoff,
    const int* __restrict__ csr, const float* __restrict__ b1,
    u16* __restrict__ out, int n)
{
  int node = (blockIdx.x * 256 + threadIdx.x) >> 6;
  int lane = threadIdx.x & 63;
  if (node >= n) return;
  const unsigned head = lane >> 4;
  const unsigned dimbase = lane * 8;
  int e0 = rowoff[node], e1 = rowoff[node + 1];
  float advn = ad1[((unsigned)node << 2) + head];

  float acc[8];
#pragma unroll
  for (int j = 0; j < 8; ++j) acc[j] = 0.f;
  float den = 0.f;

  for (int e = e0; e < e1; ++e) {
    unsigned s = (unsigned)csr[e];
    float t = as1[(s << 2) + head] + advn;
    float l = fmaxf(t, 0.2f * t);          // leaky_relu, branchless
    float ex = __expf(l);
    den += ex;
    bf16x8_t hv = *reinterpret_cast<const bf16x8_t*>(h1 + ((s << 9) + dimbase));
#pragma unroll
    for (int j = 0; j < 8; ++j) acc[j] = fmaf(ex, bf2f((u16)hv[j]), acc[j]);
  }

  float inv = 1.f / (den + 1e-16f);
  u16* orow = out + (((unsigned)node << 9) + dimbase);
#pragma unroll
  for (int j = 0; j < 8; ++j) {
    float v = acc[j] * inv + b1[dimbase + j];
    v = v > 0.f ? v : (__expf(v) - 1.0f);   // ELU (abs err ~1e-7 << bf16 eps)
    orow[j] = f2bf(v);
  }
}

// ---------------- agg2: half-wave per node, fused softmax ----------------
__global__ __launch_bounds__(256) void agg2_kernel(
    const u16* __restrict__ h2, const float* __restrict__ as2,
    const float* __restrict__ ad2, const int* __restrict__ rowoff,
    const int* __restrict__ csr, const float* __restrict__ b2,
    float* __restrict__ out, int n)
{
  int node = (blockIdx.x * 256 + threadIdx.x) >> 5;
  int l32 = threadIdx.x & 31;
  if (node >= n) return;
  int e0 = rowoff[node], e1 = rowoff[node + 1];
  float advn = ad2[node];

  float acc0 = 0.f, acc1 = 0.f, den = 0.f;
  for (int e = e0; e < e1; ++e) {
    unsigned s = (unsigned)csr[e];
    float t = as2[s] + advn;
    float l = fmaxf(t, 0.2f * t);
    float ex = __expf(l);
    den += ex;
    unsigned hv = *reinterpret_cast<const unsigned*>(h2 + (s << 6) + l32 * 2);
    acc0 = fmaf(ex, bf2f((u16)(hv & 0xffffu)), acc0);
    acc1 = fmaf(ex, bf2f((u16)(hv >> 16)), acc1);
  }
  float inv = 1.f / (den + 1e-16f);
  float2 o;
  o.x = acc0 * inv + b2[l32 * 2];
  o.y = acc1 * inv + b2[l32 * 2 + 1];
  *reinterpret_cast<float2*>(out + (((size_t)node) << 6) + l32 * 2) = o;
}

// ---------------- launch ----------------
extern "C" void kernel_launch(void* const* d_in, const int* in_sizes, int n_in,
                              void* d_out, int out_size, void* d_ws, size_t ws_size,
                              hipStream_t stream) {
  const float* x   = (const float*)d_in[0];
  const int*   ei  = (const int*)d_in[1];
  const float* W1  = (const float*)d_in[3];
  const float* a1s = (const float*)d_in[4];
  const float* a1d = (const float*)d_in[5];
  const float* b1  = (const float*)d_in[6];
  const float* W2  = (const float*)d_in[7];
  const float* a2s = (const float*)d_in[8];
  const float* a2d = (const float*)d_in[9];
  const float* b2  = (const float*)d_in[10];
  float* out = (float*)d_out;

  const int IN_DIM = 256, H1D1 = 512, D2 = 64;
  const int N = in_sizes[0] / IN_DIM;
  const int E = in_sizes[1] / 2;

  char* ws = (char*)d_ws;
  size_t off = 0;
  auto alloc = [&](size_t bytes) -> void* {
    void* p = ws + off;
    off += (bytes + 255) & ~(size_t)255;
    return p;
  };
  u16*  w1t    = (u16*)alloc((size_t)H1D1 * IN_DIM * 2);
  u16*  w2t    = (u16*)alloc((size_t)D2 * H1D1 * 2);
  u16*  h1b    = (u16*)alloc((size_t)N * H1D1 * 2);
  int*  cnt    = (int*)alloc((size_t)N * 4);
  float* as1   = (float*)alloc((size_t)N * 4 * 4);
  float* ad1   = (float*)alloc((size_t)N * 4 * 4);
  float* as2   = (float*)alloc((size_t)N * 4);
  float* ad2   = (float*)alloc((size_t)N * 4);
  int*  cursor = (int*)alloc((size_t)N * 4);
  int*  rowoff = (int*)alloc((size_t)(N + 1) * 4);
  int*  bsum   = (int*)alloc(256 * 4);
  int*  csr    = (int*)alloc((size_t)(E + N) * 4);
  u16*  h1o    = (u16*)alloc((size_t)N * H1D1 * 2);
  u16*  h2b    = (u16*)alloc((size_t)N * D2 * 2);
  (void)n_in; (void)out_size; (void)ws_size;

  const int* esrc = ei;
  const int* edst = ei + E;

  (void)hipMemsetAsync(cnt, 0, (size_t)N * 4, stream);

  int eb = (E + 255) / 256;
  prep_kernel<<<640 + eb, 256, 0, stream>>>(W1, W2, edst, w1t, w2t, cnt, E);

  // gemm1: BM=128, NP=4 col-panels, XCD-grouped padded grid
  const int NRB = (N + 127) / 128;
  const int g1 = ((NRB + 7) / 8) * 8 * 4;
  gemm1_alpha_kernel<128, 128, 4, 256, 64, 4, 4, 128><<<g1, 256, 0, stream>>>(
      x, w1t, h1b, a1s, a1d, as1, ad1, N);

  int nsb = (N + 255) / 256;
  scan_a_kernel<<<nsb, 256, 0, stream>>>(cnt, bsum, N);
  scan_c_kernel<<<nsb, 256, 0, stream>>>(cnt, bsum, rowoff, cursor, N);
  scatter_kernel<<<(E + N + 255) / 256, 256, 0, stream>>>(esrc, edst, cursor, csr, E, N);

  agg1_kernel<<<(N + 3) / 4, 256, 0, stream>>>(h1b, as1, ad1, rowoff, csr, b1, h1o, N);

  dim3 g2((N + 63) / 64, 1);
  gemm_alpha_kernel<64, 64, 4, 512, 64, 1, 64><<<g2, 256, 0, stream>>>(
      h1o, w2t, h2b, a2s, a2d, as2, ad2, N, D2);

  agg2_kernel<<<((size_t)N * 32 + 255) / 256, 256, 0, stream>>>(h2b, as2, ad2, rowoff, csr, b2, out, N);
}

// Round 17
// 223.436 us; speedup vs baseline: 1.0351x; 1.0351x over previous
//
#include <hip/hip_runtime.h>
#include <cstdint>

typedef unsigned short u16;
typedef short bf16x8_t __attribute__((ext_vector_type(8)));
typedef float f32x4_t __attribute__((ext_vector_type(4)));

#define DEVFN __device__ __forceinline__

DEVFN u16 f2bf(float f) {
  unsigned u = __builtin_bit_cast(unsigned, f);
  u = (u + 0x7fffu + ((u >> 16) & 1u)) >> 16;
  return (u16)u;
}
DEVFN float bf2f(u16 s) {
  unsigned u = ((unsigned)s) << 16;
  return __builtin_bit_cast(float, u);
}
DEVFN unsigned pk2bf(float a, float b) {
  return (unsigned)f2bf(a) | ((unsigned)f2bf(b) << 16);
}

// global -> LDS direct copy, 16B per lane; LDS dest linear in lane order.
DEVFN void gload_lds16(const u16* g, u16* l) {
  __builtin_amdgcn_global_load_lds(
      (const __attribute__((address_space(1))) void*)g,
      (__attribute__((address_space(3))) void*)l, 16, 0, 0);
}

// ---------------- prep: W1/W2 transpose->bf16, deg histogram ----------------
__global__ void prep_kernel(const float* __restrict__ W1, const float* __restrict__ W2,
                            const int* __restrict__ edst,
                            u16* __restrict__ w1t, u16* __restrict__ w2t,
                            int* __restrict__ cnt, int e) {
  int b = blockIdx.x;
  if (b < 512) {                         // W1 [256][512] -> w1t [512][256]
    int idx = b * 256 + threadIdx.x;
    int k = idx >> 9, m = idx & 511;
    w1t[m * 256 + k] = f2bf(W1[idx]);
  } else if (b < 640) {                  // W2 [512][64] -> w2t [64][512]
    int idx = (b - 512) * 256 + threadIdx.x;
    int k = idx >> 6, m = idx & 63;
    w2t[m * 512 + k] = f2bf(W2[idx]);
  } else {                               // deg histogram
    int i = (b - 640) * 256 + threadIdx.x;
    if (i < e) atomicAdd(&cnt[edst[i]], 1);
  }
}

// ===== GEMM1: f32 A fused convert, swizzled LDS, MULTI-TILE blocks ===========
// A[M][K] f32 @ BT[NP*BN][K] bf16 -> C[M][NP*BN] bf16 + fused alpha dots.
// Each block processes TPB consecutive row-blocks (r = gx*TPB + t), amortizing
// prologue/epilogue across tiles (4 K-steps/tile was too short-lived; R16's
// explicit pipeline regressed 3x -- keep R15's single-buffered K-step verbatim).
// Grid (G, NP) with G % 8 == 0: the NP panel-blocks sharing an A row-chunk have
// bids {gx + G*p}, all == gx (mod 8) -> same XCD under round-robin dispatch.
// T2 swizzle (BK=64, 128B rows): slot' = slot ^ (row&7); read col ^= (rsel&7)*8.
template<int BM, int BN, int WROWS, int K, int BK, int TPB, int H, int DH>
__global__ __launch_bounds__(256) void gemm1_alpha_kernel(
    const float* __restrict__ A, const u16* __restrict__ BT, u16* __restrict__ C,
    const float* __restrict__ a_s, const float* __restrict__ a_d,
    float* __restrict__ as_out, float* __restrict__ ad_out, int M, int NRB, int Nout)
{
  constexpr int WM = BM / WROWS;
  constexpr int MF = WM / 16;
  constexpr int NF = BN / 16;
  constexpr int KK = BK / 32;
  static_assert(BK == 64, "swizzle derived for 128B rows");
  __shared__ __align__(16) u16 sA[BM][BK];
  __shared__ __align__(16) u16 sB[BN][BK];

  const int tid = threadIdx.x;
  const int lane = tid & 63;
  const int wr = tid >> 6;
  const int bcol = blockIdx.y * BN;

  const int rsel = lane & 15;
  const int kgrp = (lane >> 4) * 8;
  const int rx = (rsel & 7) * 8;       // read-side XOR (u16 units)
  const int crow0 = (lane >> 4) * 4;
  const int ccol = lane & 15;
  const int head = bcol / DH;

  float asv[NF], adv[NF];
#pragma unroll
  for (int j = 0; j < NF; ++j) {
    int gc = bcol + j * 16 + ccol;
    asv[j] = a_s[gc];
    adv[j] = a_d[gc];
  }

  for (int t = 0; t < TPB; ++t) {
    const int r = blockIdx.x * TPB + t;
    if (r >= NRB) break;
    const int brow = r * BM;

    f32x4_t acc[MF][NF];
#pragma unroll
    for (int i = 0; i < MF; ++i)
#pragma unroll
      for (int j = 0; j < NF; ++j) acc[i][j] = f32x4_t{0.f, 0.f, 0.f, 0.f};

#pragma unroll
    for (int k0 = 0; k0 < K; k0 += BK) {
      // stage A: f32 global -> regs -> bf16 pack -> swizzled ds_write_b128
      constexpr int RA = BM * BK / 2048;   // 4 rounds
#pragma unroll
      for (int c = 0; c < RA; ++c) {
        int tt = c * 256 + tid;
        int row = tt >> 3;
        int gr = brow + row; gr = gr < M ? gr : M - 1;
        const float* src = A + (size_t)gr * K + k0 + (tt & 7) * 8;
        float4 v0 = *reinterpret_cast<const float4*>(src);
        float4 v1 = *reinterpret_cast<const float4*>(src + 4);
        uint4 pk;
        pk.x = pk2bf(v0.x, v0.y);
        pk.y = pk2bf(v0.z, v0.w);
        pk.z = pk2bf(v1.x, v1.y);
        pk.w = pk2bf(v1.z, v1.w);
        int slot = (tt & 7) ^ (row & 7);
        *reinterpret_cast<uint4*>(&sA[0][0] + row * BK + slot * 8) = pk;
      }
      // stage B via global_load_lds with pre-swizzled source column (L2-hot)
      constexpr int RB = BN * BK / 2048;
#pragma unroll
      for (int c = 0; c < RB; ++c) {
        int tt = c * 256 + tid;
        int row = tt >> 3;
        int col = ((tt & 7) ^ (row & 7)) * 8;
        gload_lds16(BT + (size_t)(bcol + row) * K + k0 + col, &sB[0][0] + tt * 8);
      }
      __syncthreads();
#pragma unroll
      for (int kk = 0; kk < KK; ++kk) {
        const int cswz = (kk * 32 + kgrp) ^ rx;
        bf16x8_t af[MF], bfr[NF];
#pragma unroll
        for (int i = 0; i < MF; ++i) {
          int row = wr * WM + i * 16 + rsel;
          af[i] = *reinterpret_cast<const bf16x8_t*>(&sA[0][0] + row * BK + cswz);
        }
#pragma unroll
        for (int j = 0; j < NF; ++j) {
          int row = j * 16 + rsel;
          bfr[j] = *reinterpret_cast<const bf16x8_t*>(&sB[0][0] + row * BK + cswz);
        }
#pragma unroll
        for (int i = 0; i < MF; ++i)
#pragma unroll
          for (int j = 0; j < NF; ++j)
            acc[i][j] = __builtin_amdgcn_mfma_f32_16x16x32_bf16(af[i], bfr[j], acc[i][j], 0, 0, 0);
      }
      __syncthreads();
    }

    // epilogue: C write (registers + global only; LDS free for next tile)
#pragma unroll
    for (int i = 0; i < MF; ++i)
#pragma unroll
      for (int j = 0; j < NF; ++j)
#pragma unroll
        for (int rr = 0; rr < 4; ++rr) {
          int gr = brow + wr * WM + i * 16 + crow0 + rr;
          int gc = bcol + j * 16 + ccol;
          if (gr < M) C[(size_t)gr * Nout + gc] = f2bf(acc[i][j][rr]);
        }

    // fused alpha dots (1 wave owns a row; BN==DH so one block owns (row, head))
#pragma unroll
    for (int i = 0; i < MF; ++i) {
#pragma unroll
      for (int rr = 0; rr < 4; ++rr) {
        float ps = 0.f, pd = 0.f;
#pragma unroll
        for (int j = 0; j < NF; ++j) {
          float v = acc[i][j][rr];
          ps = fmaf(v, asv[j], ps);
          pd = fmaf(v, adv[j], pd);
        }
#pragma unroll
        for (int d = 1; d < 16; d <<= 1) {
          ps += __shfl_xor(ps, d, 64);
          pd += __shfl_xor(pd, d, 64);
        }
        if ((lane & 15) == 0) {
          int gr = brow + wr * WM + i * 16 + crow0 + rr;
          if (gr < M) {
            as_out[(size_t)gr * H + head] = ps;
            ad_out[(size_t)gr * H + head] = pd;
          }
        }
      }
    }
  }
}

// ---------------- GEMM2 (swizzled gload_lds, BK=64) + fused alpha2 dots -------
template<int BM, int BN, int WROWS, int K, int BK, int H, int DH>
__global__ __launch_bounds__(256) void gemm_alpha_kernel(
    const u16* __restrict__ A, const u16* __restrict__ BT, u16* __restrict__ C,
    const float* __restrict__ a_s, const float* __restrict__ a_d,
    float* __restrict__ as_out, float* __restrict__ ad_out, int M, int N)
{
  static_assert(BN == DH, "alpha store ownership");
  static_assert(BK == 64, "swizzle derived for 128B rows");
  constexpr int WM = BM / WROWS;
  constexpr int MF = WM / 16;
  constexpr int NF = BN / 16;
  constexpr int KK = BK / 32;
  __shared__ __align__(16) u16 sA[BM][BK];
  __shared__ __align__(16) u16 sB[BN][BK];

  const int tid = threadIdx.x;
  const int lane = tid & 63;
  const int wr = tid >> 6;
  const int brow = blockIdx.x * BM;
  const int bcol = blockIdx.y * BN;

  f32x4_t acc[MF][NF];
#pragma unroll
  for (int i = 0; i < MF; ++i)
#pragma unroll
    for (int j = 0; j < NF; ++j) acc[i][j] = f32x4_t{0.f, 0.f, 0.f, 0.f};

  const int rsel = lane & 15;
  const int kgrp = (lane >> 4) * 8;
  const int rx = (rsel & 7) * 8;

#pragma unroll
  for (int k0 = 0; k0 < K; k0 += BK) {
    constexpr int RA = BM * BK / 2048;
#pragma unroll
    for (int c = 0; c < RA; ++c) {
      int t = c * 256 + tid;
      int row = t >> 3;
      int col = ((t & 7) ^ (row & 7)) * 8;
      int gr = brow + row; gr = gr < M ? gr : M - 1;
      gload_lds16(A + (size_t)gr * K + k0 + col, &sA[0][0] + t * 8);
    }
    constexpr int RB = BN * BK / 2048;
#pragma unroll
    for (int c = 0; c < RB; ++c) {
      int t = c * 256 + tid;
      int row = t >> 3;
      int col = ((t & 7) ^ (row & 7)) * 8;
      gload_lds16(BT + (size_t)(bcol + row) * K + k0 + col, &sB[0][0] + t * 8);
    }
    __syncthreads();
#pragma unroll
    for (int kk = 0; kk < KK; ++kk) {
      const int cswz = (kk * 32 + kgrp) ^ rx;
      bf16x8_t af[MF], bfr[NF];
#pragma unroll
      for (int i = 0; i < MF; ++i) {
        int row = wr * WM + i * 16 + rsel;
        af[i] = *reinterpret_cast<const bf16x8_t*>(&sA[0][0] + row * BK + cswz);
      }
#pragma unroll
      for (int j = 0; j < NF; ++j) {
        int row = j * 16 + rsel;
        bfr[j] = *reinterpret_cast<const bf16x8_t*>(&sB[0][0] + row * BK + cswz);
      }
#pragma unroll
      for (int i = 0; i < MF; ++i)
#pragma unroll
        for (int j = 0; j < NF; ++j)
          acc[i][j] = __builtin_amdgcn_mfma_f32_16x16x32_bf16(af[i], bfr[j], acc[i][j], 0, 0, 0);
    }
    __syncthreads();
  }

  const int crow0 = (lane >> 4) * 4;
  const int ccol = lane & 15;

#pragma unroll
  for (int i = 0; i < MF; ++i)
#pragma unroll
    for (int j = 0; j < NF; ++j)
#pragma unroll
      for (int rr = 0; rr < 4; ++rr) {
        int gr = brow + wr * WM + i * 16 + crow0 + rr;
        int gc = bcol + j * 16 + ccol;
        if (gr < M) C[(size_t)gr * N + gc] = f2bf(acc[i][j][rr]);
      }

  const int head = bcol / DH;
  float asv[NF], adv[NF];
#pragma unroll
  for (int j = 0; j < NF; ++j) {
    int gc = bcol + j * 16 + ccol;
    asv[j] = a_s[gc];
    adv[j] = a_d[gc];
  }
#pragma unroll
  for (int i = 0; i < MF; ++i) {
#pragma unroll
    for (int rr = 0; rr < 4; ++rr) {
      float ps = 0.f, pd = 0.f;
#pragma unroll
      for (int j = 0; j < NF; ++j) {
        float v = acc[i][j][rr];
        ps = fmaf(v, asv[j], ps);
        pd = fmaf(v, adv[j], pd);
      }
#pragma unroll
      for (int d = 1; d < 16; d <<= 1) {
        ps += __shfl_xor(ps, d, 64);
        pd += __shfl_xor(pd, d, 64);
      }
      if ((lane & 15) == 0) {
        int gr = brow + wr * WM + i * 16 + crow0 + rr;
        if (gr < M) {
          as_out[(size_t)gr * H + head] = ps;
          ad_out[(size_t)gr * H + head] = pd;
        }
      }
    }
  }
}

// ---------------- CSR build ----------------
DEVFN int block_scan_256(int v, int tid, int* wsum) {
#pragma unroll
  for (int d = 1; d < 64; d <<= 1) {
    int u = __shfl_up(v, d, 64);
    if ((tid & 63) >= d) v += u;
  }
  if ((tid & 63) == 63) wsum[tid >> 6] = v;
  __syncthreads();
  int add = 0;
#pragma unroll
  for (int w = 0; w < 4; ++w) add += (w < (tid >> 6)) ? wsum[w] : 0;
  __syncthreads();
  return v + add;
}

__global__ __launch_bounds__(256) void scan_a_kernel(const int* __restrict__ cnt, int* __restrict__ bsum, int n) {
  __shared__ int ws4[4];
  int i = blockIdx.x * 256 + threadIdx.x;
  int v = (i < n) ? cnt[i] + 1 : 0;   // +1 self loop
  int incl = block_scan_256(v, threadIdx.x, ws4);
  if (threadIdx.x == 255) bsum[blockIdx.x] = incl;
}

__global__ __launch_bounds__(256) void scan_c_kernel(
    const int* __restrict__ cnt, const int* __restrict__ bsum,
    int* __restrict__ rowoff, int* __restrict__ cursor, int n)
{
  __shared__ int ws4[4];
  __shared__ int ws4b[4];
  __shared__ int base_sh;
  int pre = 0;
  for (int w = threadIdx.x; w < blockIdx.x; w += 256) pre += bsum[w];
#pragma unroll
  for (int d = 1; d < 64; d <<= 1) pre += __shfl_xor(pre, d, 64);
  if ((threadIdx.x & 63) == 0) ws4b[threadIdx.x >> 6] = pre;
  __syncthreads();
  if (threadIdx.x == 0) base_sh = ws4b[0] + ws4b[1] + ws4b[2] + ws4b[3];
  int i = blockIdx.x * 256 + threadIdx.x;
  int v = (i < n) ? cnt[i] + 1 : 0;
  int incl = block_scan_256(v, threadIdx.x, ws4);
  int off = base_sh + incl - v;
  if (i < n) {
    rowoff[i] = off;
    cursor[i] = off;
    if (i == n - 1) rowoff[n] = off + v;
  }
}

__global__ void scatter_kernel(const int* __restrict__ srcs, const int* __restrict__ dsts,
                               int* __restrict__ cursor, int* __restrict__ csr, int e, int n) {
  int i = blockIdx.x * 256 + threadIdx.x;
  if (i >= e + n) return;
  int s, d;
  if (i < e) { s = srcs[i]; d = dsts[i]; }
  else       { s = i - e; d = s; }
  int pos = atomicAdd(&cursor[d], 1);
  csr[pos] = s;
}

// ---------------- agg1: gather h1b, fused softmax (no-max-shift), b1+ELU -------
__global__ __launch_bounds__(256) void agg1_kernel(
    const u16* __restrict__ h1, const float* __restrict__ as1,
    const float* __restrict__ ad1, const int* __restrict__ rowoff,
    const int* __restrict__ csr, const float* __restrict__ b1,
    u16* __restrict__ out, int n)
{
  int node = (blockIdx.x * 256 + threadIdx.x) >> 6;
  int lane = threadIdx.x & 63;
  if (node >= n) return;
  const unsigned head = lane >> 4;
  const unsigned dimbase = lane * 8;
  int e0 = rowoff[node], e1 = rowoff[node + 1];
  float advn = ad1[((unsigned)node << 2) + head];

  float acc[8];
#pragma unroll
  for (int j = 0; j < 8; ++j) acc[j] = 0.f;
  float den = 0.f;

  for (int e = e0; e < e1; ++e) {
    unsigned s = (unsigned)csr[e];
    float t = as1[(s << 2) + head] + advn;
    float l = fmaxf(t, 0.2f * t);          // leaky_relu, branchless
    float ex = __expf(l);
    den += ex;
    bf16x8_t hv = *reinterpret_cast<const bf16x8_t*>(h1 + ((s << 9) + dimbase));
#pragma unroll
    for (int j = 0; j < 8; ++j) acc[j] = fmaf(ex, bf2f((u16)hv[j]), acc[j]);
  }

  float inv = 1.f / (den + 1e-16f);
  u16* orow = out + (((unsigned)node << 9) + dimbase);
#pragma unroll
  for (int j = 0; j < 8; ++j) {
    float v = acc[j] * inv + b1[dimbase + j];
    v = v > 0.f ? v : (__expf(v) - 1.0f);   // ELU (abs err ~1e-7 << bf16 eps)
    orow[j] = f2bf(v);
  }
}

// ---------------- agg2: half-wave per node, fused softmax ----------------
__global__ __launch_bounds__(256) void agg2_kernel(
    const u16* __restrict__ h2, const float* __restrict__ as2,
    const float* __restrict__ ad2, const int* __restrict__ rowoff,
    const int* __restrict__ csr, const float* __restrict__ b2,
    float* __restrict__ out, int n)
{
  int node = (blockIdx.x * 256 + threadIdx.x) >> 5;
  int l32 = threadIdx.x & 31;
  if (node >= n) return;
  int e0 = rowoff[node], e1 = rowoff[node + 1];
  float advn = ad2[node];

  float acc0 = 0.f, acc1 = 0.f, den = 0.f;
  for (int e = e0; e < e1; ++e) {
    unsigned s = (unsigned)csr[e];
    float t = as2[s] + advn;
    float l = fmaxf(t, 0.2f * t);
    float ex = __expf(l);
    den += ex;
    unsigned hv = *reinterpret_cast<const unsigned*>(h2 + (s << 6) + l32 * 2);
    acc0 = fmaf(ex, bf2f((u16)(hv & 0xffffu)), acc0);
    acc1 = fmaf(ex, bf2f((u16)(hv >> 16)), acc1);
  }
  float inv = 1.f / (den + 1e-16f);
  float2 o;
  o.x = acc0 * inv + b2[l32 * 2];
  o.y = acc1 * inv + b2[l32 * 2 + 1];
  *reinterpret_cast<float2*>(out + (((size_t)node) << 6) + l32 * 2) = o;
}

// ---------------- launch ----------------
extern "C" void kernel_launch(void* const* d_in, const int* in_sizes, int n_in,
                              void* d_out, int out_size, void* d_ws, size_t ws_size,
                              hipStream_t stream) {
  const float* x   = (const float*)d_in[0];
  const int*   ei  = (const int*)d_in[1];
  const float* W1  = (const float*)d_in[3];
  const float* a1s = (const float*)d_in[4];
  const float* a1d = (const float*)d_in[5];
  const float* b1  = (const float*)d_in[6];
  const float* W2  = (const float*)d_in[7];
  const float* a2s = (const float*)d_in[8];
  const float* a2d = (const float*)d_in[9];
  const float* b2  = (const float*)d_in[10];
  float* out = (float*)d_out;

  const int IN_DIM = 256, H1D1 = 512, D2 = 64;
  const int N = in_sizes[0] / IN_DIM;
  const int E = in_sizes[1] / 2;

  char* ws = (char*)d_ws;
  size_t off = 0;
  auto alloc = [&](size_t bytes) -> void* {
    void* p = ws + off;
    off += (bytes + 255) & ~(size_t)255;
    return p;
  };
  u16*  w1t    = (u16*)alloc((size_t)H1D1 * IN_DIM * 2);
  u16*  w2t    = (u16*)alloc((size_t)D2 * H1D1 * 2);
  u16*  h1b    = (u16*)alloc((size_t)N * H1D1 * 2);
  int*  cnt    = (int*)alloc((size_t)N * 4);
  float* as1   = (float*)alloc((size_t)N * 4 * 4);
  float* ad1   = (float*)alloc((size_t)N * 4 * 4);
  float* as2   = (float*)alloc((size_t)N * 4);
  float* ad2   = (float*)alloc((size_t)N * 4);
  int*  cursor = (int*)alloc((size_t)N * 4);
  int*  rowoff = (int*)alloc((size_t)(N + 1) * 4);
  int*  bsum   = (int*)alloc(256 * 4);
  int*  csr    = (int*)alloc((size_t)(E + N) * 4);
  u16*  h1o    = (u16*)alloc((size_t)N * H1D1 * 2);
  u16*  h2b    = (u16*)alloc((size_t)N * D2 * 2);
  (void)n_in; (void)out_size; (void)ws_size;

  const int* esrc = ei;
  const int* edst = ei + E;

  (void)hipMemsetAsync(cnt, 0, (size_t)N * 4, stream);

  int eb = (E + 255) / 256;
  prep_kernel<<<640 + eb, 256, 0, stream>>>(W1, W2, edst, w1t, w2t, cnt, E);

  // gemm1: TPB=2 row-blocks per block; G rounded to multiple of 8 so the 4
  // panel-blocks sharing an A chunk land on one XCD (bids gx + G*p).
  const int NRB = (N + 127) / 128;
  const int G1 = (((NRB + 1) / 2) + 7) & ~7;
  dim3 g1(G1, 4);
  gemm1_alpha_kernel<128, 128, 4, 256, 64, 2, 4, 128><<<g1, 256, 0, stream>>>(
      x, w1t, h1b, a1s, a1d, as1, ad1, N, NRB, H1D1);

  int nsb = (N + 255) / 256;
  scan_a_kernel<<<nsb, 256, 0, stream>>>(cnt, bsum, N);
  scan_c_kernel<<<nsb, 256, 0, stream>>>(cnt, bsum, rowoff, cursor, N);
  scatter_kernel<<<(E + N + 255) / 256, 256, 0, stream>>>(esrc, edst, cursor, csr, E, N);

  agg1_kernel<<<(N + 3) / 4, 256, 0, stream>>>(h1b, as1, ad1, rowoff, csr, b1, h1o, N);

  dim3 g2((N + 63) / 64, 1);
  gemm_alpha_kernel<64, 64, 4, 512, 64, 1, 64><<<g2, 256, 0, stream>>>(
      h1o, w2t, h2b, a2s, a2d, as2, ad2, N, D2);

  agg2_kernel<<<((size_t)N * 32 + 255) / 256, 256, 0, stream>>>(h2b, as2, ad2, rowoff, csr, b2, out, N);
}

// Round 18
// 222.607 us; speedup vs baseline: 1.0390x; 1.0037x over previous
//
#include <hip/hip_runtime.h>
#include <cstdint>

typedef unsigned short u16;
typedef short bf16x8_t __attribute__((ext_vector_type(8)));
typedef float f32x4_t __attribute__((ext_vector_type(4)));

#define DEVFN __device__ __forceinline__

DEVFN u16 f2bf(float f) {
  unsigned u = __builtin_bit_cast(unsigned, f);
  u = (u + 0x7fffu + ((u >> 16) & 1u)) >> 16;
  return (u16)u;
}
DEVFN float bf2f(u16 s) {
  unsigned u = ((unsigned)s) << 16;
  return __builtin_bit_cast(float, u);
}
DEVFN unsigned pk2bf(float a, float b) {
  return (unsigned)f2bf(a) | ((unsigned)f2bf(b) << 16);
}

// global -> LDS direct copy, 16B per lane; LDS dest linear in lane order.
DEVFN void gload_lds16(const u16* g, u16* l) {
  __builtin_amdgcn_global_load_lds(
      (const __attribute__((address_space(1))) void*)g,
      (__attribute__((address_space(3))) void*)l, 16, 0, 0);
}

// ---------------- prep: W1/W2 transpose->bf16, deg histogram ----------------
__global__ void prep_kernel(const float* __restrict__ W1, const float* __restrict__ W2,
                            const int* __restrict__ edst,
                            u16* __restrict__ w1t, u16* __restrict__ w2t,
                            int* __restrict__ cnt, int e) {
  int b = blockIdx.x;
  if (b < 512) {                         // W1 [256][512] -> w1t [512][256]
    int idx = b * 256 + threadIdx.x;
    int k = idx >> 9, m = idx & 511;
    w1t[m * 256 + k] = f2bf(W1[idx]);
  } else if (b < 640) {                  // W2 [512][64] -> w2t [64][512]
    int idx = (b - 512) * 256 + threadIdx.x;
    int k = idx >> 6, m = idx & 63;
    w2t[m * 512 + k] = f2bf(W2[idx]);
  } else {                               // deg histogram
    int i = (b - 640) * 256 + threadIdx.x;
    if (i < e) atomicAdd(&cnt[edst[i]], 1);
  }
}

// ================= GEMM1 (R15 config): f32 A fused convert, swizzled, XCD-grouped
// A[M][K] f32 @ BT[NP*BN][K] bf16 -> C[M][NP*BN] bf16 + fused alpha dots.
// The NP col-panel blocks sharing one A row-block get the same bid%8 (same XCD
// under round-robin dispatch) -> A panel fetched into that XCD's L2 once.
// T2 swizzle (BK=64, 128B rows): A reg-staged with swizzled ds_write slot;
// B gload_lds with pre-swizzled source column; reads XOR the same pattern.
template<int BM, int BN, int WROWS, int K, int BK, int NP, int H, int DH>
__global__ __launch_bounds__(256) void gemm1_alpha_kernel(
    const float* __restrict__ A, const u16* __restrict__ BT, u16* __restrict__ C,
    const float* __restrict__ a_s, const float* __restrict__ a_d,
    float* __restrict__ as_out, float* __restrict__ ad_out, int M)
{
  constexpr int N = NP * BN;
  constexpr int WM = BM / WROWS;
  constexpr int MF = WM / 16;
  constexpr int NF = BN / 16;
  constexpr int KK = BK / 32;
  static_assert(BK == 64, "swizzle derived for 128B rows");
  __shared__ __align__(16) u16 sA[BM][BK];
  __shared__ __align__(16) u16 sB[BN][BK];

  const int tid = threadIdx.x;
  const int lane = tid & 63;
  const int wr = tid >> 6;

  const int bid = blockIdx.x;
  const int xcd = bid & 7;
  const int rest = bid >> 3;
  const int p = rest & (NP - 1);
  const int rb = rest / NP;
  const int r = rb * 8 + xcd;
  const int NRB = (M + BM - 1) / BM;
  if (r >= NRB) return;
  const int brow = r * BM;
  const int bcol = p * BN;

  f32x4_t acc[MF][NF];
#pragma unroll
  for (int i = 0; i < MF; ++i)
#pragma unroll
    for (int j = 0; j < NF; ++j) acc[i][j] = f32x4_t{0.f, 0.f, 0.f, 0.f};

  const int rsel = lane & 15;
  const int kgrp = (lane >> 4) * 8;
  const int rx = (rsel & 7) * 8;       // read-side XOR (u16 units)

#pragma unroll
  for (int k0 = 0; k0 < K; k0 += BK) {
    // stage A: f32 global -> regs -> bf16 pack -> swizzled ds_write_b128
    constexpr int RA = BM * BK / 2048;   // 4 rounds
#pragma unroll
    for (int c = 0; c < RA; ++c) {
      int t = c * 256 + tid;
      int row = t >> 3;
      int gr = brow + row; gr = gr < M ? gr : M - 1;
      const float* src = A + (size_t)gr * K + k0 + (t & 7) * 8;
      float4 v0 = *reinterpret_cast<const float4*>(src);
      float4 v1 = *reinterpret_cast<const float4*>(src + 4);
      uint4 pk;
      pk.x = pk2bf(v0.x, v0.y);
      pk.y = pk2bf(v0.z, v0.w);
      pk.z = pk2bf(v1.x, v1.y);
      pk.w = pk2bf(v1.z, v1.w);
      int slot = (t & 7) ^ (row & 7);
      *reinterpret_cast<uint4*>(&sA[0][0] + row * BK + slot * 8) = pk;
    }
    // stage B via global_load_lds with pre-swizzled source column (L2-hot)
    constexpr int RB = BN * BK / 2048;
#pragma unroll
    for (int c = 0; c < RB; ++c) {
      int t = c * 256 + tid;
      int row = t >> 3;
      int col = ((t & 7) ^ (row & 7)) * 8;
      gload_lds16(BT + (size_t)(bcol + row) * K + k0 + col, &sB[0][0] + t * 8);
    }
    __syncthreads();
#pragma unroll
    for (int kk = 0; kk < KK; ++kk) {
      const int cswz = (kk * 32 + kgrp) ^ rx;
      bf16x8_t af[MF], bfr[NF];
#pragma unroll
      for (int i = 0; i < MF; ++i) {
        int row = wr * WM + i * 16 + rsel;
        af[i] = *reinterpret_cast<const bf16x8_t*>(&sA[0][0] + row * BK + cswz);
      }
#pragma unroll
      for (int j = 0; j < NF; ++j) {
        int row = j * 16 + rsel;
        bfr[j] = *reinterpret_cast<const bf16x8_t*>(&sB[0][0] + row * BK + cswz);
      }
#pragma unroll
      for (int i = 0; i < MF; ++i)
#pragma unroll
        for (int j = 0; j < NF; ++j)
          acc[i][j] = __builtin_amdgcn_mfma_f32_16x16x32_bf16(af[i], bfr[j], acc[i][j], 0, 0, 0);
    }
    __syncthreads();
  }

  const int crow0 = (lane >> 4) * 4;
  const int ccol = lane & 15;

  // C write
#pragma unroll
  for (int i = 0; i < MF; ++i)
#pragma unroll
    for (int j = 0; j < NF; ++j)
#pragma unroll
      for (int rr = 0; rr < 4; ++rr) {
        int gr = brow + wr * WM + i * 16 + crow0 + rr;
        int gc = bcol + j * 16 + ccol;
        if (gr < M) C[(size_t)gr * N + gc] = f2bf(acc[i][j][rr]);
      }

  // fused alpha dots (1 wave owns a row; BN==DH so one block owns (row, head))
  const int head = bcol / DH;
  float asv[NF], adv[NF];
#pragma unroll
  for (int j = 0; j < NF; ++j) {
    int gc = bcol + j * 16 + ccol;
    asv[j] = a_s[gc];
    adv[j] = a_d[gc];
  }
#pragma unroll
  for (int i = 0; i < MF; ++i) {
#pragma unroll
    for (int rr = 0; rr < 4; ++rr) {
      float ps = 0.f, pd = 0.f;
#pragma unroll
      for (int j = 0; j < NF; ++j) {
        float v = acc[i][j][rr];
        ps = fmaf(v, asv[j], ps);
        pd = fmaf(v, adv[j], pd);
      }
#pragma unroll
      for (int d = 1; d < 16; d <<= 1) {
        ps += __shfl_xor(ps, d, 64);
        pd += __shfl_xor(pd, d, 64);
      }
      if ((lane & 15) == 0) {
        int gr = brow + wr * WM + i * 16 + crow0 + rr;
        if (gr < M) {
          as_out[(size_t)gr * H + head] = ps;
          ad_out[(size_t)gr * H + head] = pd;
        }
      }
    }
  }
}

// ---------------- GEMM2: A reg-staged (R11 mechanism), B gload_lds + alpha2 ----
// A (h1o, the 50 MB stream) now avoids the gload_lds vmcnt-at-barrier drain:
// plain global loads -> registers -> swizzled ds_write (compiler pipelines the
// loads). B (w2t, 64KB, L2-hot) keeps gload_lds.
template<int BM, int BN, int WROWS, int K, int BK, int H, int DH>
__global__ __launch_bounds__(256) void gemm_alpha_kernel(
    const u16* __restrict__ A, const u16* __restrict__ BT, u16* __restrict__ C,
    const float* __restrict__ a_s, const float* __restrict__ a_d,
    float* __restrict__ as_out, float* __restrict__ ad_out, int M, int N)
{
  static_assert(BN == DH, "alpha store ownership");
  static_assert(BK == 64, "swizzle derived for 128B rows");
  constexpr int WM = BM / WROWS;
  constexpr int MF = WM / 16;
  constexpr int NF = BN / 16;
  constexpr int KK = BK / 32;
  __shared__ __align__(16) u16 sA[BM][BK];
  __shared__ __align__(16) u16 sB[BN][BK];

  const int tid = threadIdx.x;
  const int lane = tid & 63;
  const int wr = tid >> 6;
  const int brow = blockIdx.x * BM;
  const int bcol = blockIdx.y * BN;

  f32x4_t acc[MF][NF];
#pragma unroll
  for (int i = 0; i < MF; ++i)
#pragma unroll
    for (int j = 0; j < NF; ++j) acc[i][j] = f32x4_t{0.f, 0.f, 0.f, 0.f};

  const int rsel = lane & 15;
  const int kgrp = (lane >> 4) * 8;
  const int rx = (rsel & 7) * 8;

#pragma unroll
  for (int k0 = 0; k0 < K; k0 += BK) {
    // stage A: bf16 global -> regs -> swizzled ds_write_b128
    constexpr int RA = BM * BK / 2048;   // 2 rounds
    bf16x8_t av[RA];
#pragma unroll
    for (int c = 0; c < RA; ++c) {
      int t = c * 256 + tid;
      int row = t >> 3;
      int gr = brow + row; gr = gr < M ? gr : M - 1;
      av[c] = *reinterpret_cast<const bf16x8_t*>(A + (size_t)gr * K + k0 + (t & 7) * 8);
    }
#pragma unroll
    for (int c = 0; c < RA; ++c) {
      int t = c * 256 + tid;
      int row = t >> 3;
      int slot = (t & 7) ^ (row & 7);
      *reinterpret_cast<bf16x8_t*>(&sA[0][0] + row * BK + slot * 8) = av[c];
    }
    // stage B via global_load_lds with pre-swizzled source column (L2-hot)
    constexpr int RB = BN * BK / 2048;
#pragma unroll
    for (int c = 0; c < RB; ++c) {
      int t = c * 256 + tid;
      int row = t >> 3;
      int col = ((t & 7) ^ (row & 7)) * 8;
      gload_lds16(BT + (size_t)(bcol + row) * K + k0 + col, &sB[0][0] + t * 8);
    }
    __syncthreads();
#pragma unroll
    for (int kk = 0; kk < KK; ++kk) {
      const int cswz = (kk * 32 + kgrp) ^ rx;
      bf16x8_t af[MF], bfr[NF];
#pragma unroll
      for (int i = 0; i < MF; ++i) {
        int row = wr * WM + i * 16 + rsel;
        af[i] = *reinterpret_cast<const bf16x8_t*>(&sA[0][0] + row * BK + cswz);
      }
#pragma unroll
      for (int j = 0; j < NF; ++j) {
        int row = j * 16 + rsel;
        bfr[j] = *reinterpret_cast<const bf16x8_t*>(&sB[0][0] + row * BK + cswz);
      }
#pragma unroll
      for (int i = 0; i < MF; ++i)
#pragma unroll
        for (int j = 0; j < NF; ++j)
          acc[i][j] = __builtin_amdgcn_mfma_f32_16x16x32_bf16(af[i], bfr[j], acc[i][j], 0, 0, 0);
    }
    __syncthreads();
  }

  const int crow0 = (lane >> 4) * 4;
  const int ccol = lane & 15;

#pragma unroll
  for (int i = 0; i < MF; ++i)
#pragma unroll
    for (int j = 0; j < NF; ++j)
#pragma unroll
      for (int rr = 0; rr < 4; ++rr) {
        int gr = brow + wr * WM + i * 16 + crow0 + rr;
        int gc = bcol + j * 16 + ccol;
        if (gr < M) C[(size_t)gr * N + gc] = f2bf(acc[i][j][rr]);
      }

  const int head = bcol / DH;
  float asv[NF], adv[NF];
#pragma unroll
  for (int j = 0; j < NF; ++j) {
    int gc = bcol + j * 16 + ccol;
    asv[j] = a_s[gc];
    adv[j] = a_d[gc];
  }
#pragma unroll
  for (int i = 0; i < MF; ++i) {
#pragma unroll
    for (int rr = 0; rr < 4; ++rr) {
      float ps = 0.f, pd = 0.f;
#pragma unroll
      for (int j = 0; j < NF; ++j) {
        float v = acc[i][j][rr];
        ps = fmaf(v, asv[j], ps);
        pd = fmaf(v, adv[j], pd);
      }
#pragma unroll
      for (int d = 1; d < 16; d <<= 1) {
        ps += __shfl_xor(ps, d, 64);
        pd += __shfl_xor(pd, d, 64);
      }
      if ((lane & 15) == 0) {
        int gr = brow + wr * WM + i * 16 + crow0 + rr;
        if (gr < M) {
          as_out[(size_t)gr * H + head] = ps;
          ad_out[(size_t)gr * H + head] = pd;
        }
      }
    }
  }
}

// ---------------- CSR build ----------------
DEVFN int block_scan_256(int v, int tid, int* wsum) {
#pragma unroll
  for (int d = 1; d < 64; d <<= 1) {
    int u = __shfl_up(v, d, 64);
    if ((tid & 63) >= d) v += u;
  }
  if ((tid & 63) == 63) wsum[tid >> 6] = v;
  __syncthreads();
  int add = 0;
#pragma unroll
  for (int w = 0; w < 4; ++w) add += (w < (tid >> 6)) ? wsum[w] : 0;
  __syncthreads();
  return v + add;
}

__global__ __launch_bounds__(256) void scan_a_kernel(const int* __restrict__ cnt, int* __restrict__ bsum, int n) {
  __shared__ int ws4[4];
  int i = blockIdx.x * 256 + threadIdx.x;
  int v = (i < n) ? cnt[i] + 1 : 0;   // +1 self loop
  int incl = block_scan_256(v, threadIdx.x, ws4);
  if (threadIdx.x == 255) bsum[blockIdx.x] = incl;
}

__global__ __launch_bounds__(256) void scan_c_kernel(
    const int* __restrict__ cnt, const int* __restrict__ bsum,
    int* __restrict__ rowoff, int* __restrict__ cursor, int n)
{
  __shared__ int ws4[4];
  __shared__ int ws4b[4];
  __shared__ int base_sh;
  int pre = 0;
  for (int w = threadIdx.x; w < blockIdx.x; w += 256) pre += bsum[w];
#pragma unroll
  for (int d = 1; d < 64; d <<= 1) pre += __shfl_xor(pre, d, 64);
  if ((threadIdx.x & 63) == 0) ws4b[threadIdx.x >> 6] = pre;
  __syncthreads();
  if (threadIdx.x == 0) base_sh = ws4b[0] + ws4b[1] + ws4b[2] + ws4b[3];
  int i = blockIdx.x * 256 + threadIdx.x;
  int v = (i < n) ? cnt[i] + 1 : 0;
  int incl = block_scan_256(v, threadIdx.x, ws4);
  int off = base_sh + incl - v;
  if (i < n) {
    rowoff[i] = off;
    cursor[i] = off;
    if (i == n - 1) rowoff[n] = off + v;
  }
}

__global__ void scatter_kernel(const int* __restrict__ srcs, const int* __restrict__ dsts,
                               int* __restrict__ cursor, int* __restrict__ csr, int e, int n) {
  int i = blockIdx.x * 256 + threadIdx.x;
  if (i >= e + n) return;
  int s, d;
  if (i < e) { s = srcs[i]; d = dsts[i]; }
  else       { s = i - e; d = s; }
  int pos = atomicAdd(&cursor[d], 1);
  csr[pos] = s;
}

// ---------------- agg1: gather h1b, fused softmax (no-max-shift), b1+ELU -------
__global__ __launch_bounds__(256) void agg1_kernel(
    const u16* __restrict__ h1, const float* __restrict__ as1,
    const float* __restrict__ ad1, const int* __restrict__ rowoff,
    const int* __restrict__ csr, const float* __restrict__ b1,
    u16* __restrict__ out, int n)
{
  int node = (blockIdx.x * 256 + threadIdx.x) >> 6;
  int lane = threadIdx.x & 63;
  if (node >= n) return;
  const unsigned head = lane >> 4;
  const unsigned dimbase = lane * 8;
  int e0 = rowoff[node], e1 = rowoff[node + 1];
  float advn = ad1[((unsigned)node << 2) + head];

  float acc[8];
#pragma unroll
  for (int j = 0; j < 8; ++j) acc[j] = 0.f;
  float den = 0.f;

  for (int e = e0; e < e1; ++e) {
    unsigned s = (unsigned)csr[e];
    float t = as1[(s << 2) + head] + advn;
    float l = fmaxf(t, 0.2f * t);          // leaky_relu, branchless
    float ex = __expf(l);
    den += ex;
    bf16x8_t hv = *reinterpret_cast<const bf16x8_t*>(h1 + ((s << 9) + dimbase));
#pragma unroll
    for (int j = 0; j < 8; ++j) acc[j] = fmaf(ex, bf2f((u16)hv[j]), acc[j]);
  }

  float inv = 1.f / (den + 1e-16f);
  u16* orow = out + (((unsigned)node << 9) + dimbase);
#pragma unroll
  for (int j = 0; j < 8; ++j) {
    float v = acc[j] * inv + b1[dimbase + j];
    v = v > 0.f ? v : (__expf(v) - 1.0f);   // ELU (abs err ~1e-7 << bf16 eps)
    orow[j] = f2bf(v);
  }
}

// ---------------- agg2: half-wave per node, fused softmax ----------------
__global__ __launch_bounds__(256) void agg2_kernel(
    const u16* __restrict__ h2, const float* __restrict__ as2,
    const float* __restrict__ ad2, const int* __restrict__ rowoff,
    const int* __restrict__ csr, const float* __restrict__ b2,
    float* __restrict__ out, int n)
{
  int node = (blockIdx.x * 256 + threadIdx.x) >> 5;
  int l32 = threadIdx.x & 31;
  if (node >= n) return;
  int e0 = rowoff[node], e1 = rowoff[node + 1];
  float advn = ad2[node];

  float acc0 = 0.f, acc1 = 0.f, den = 0.f;
  for (int e = e0; e < e1; ++e) {
    unsigned s = (unsigned)csr[e];
    float t = as2[s] + advn;
    float l = fmaxf(t, 0.2f * t);
    float ex = __expf(l);
    den += ex;
    unsigned hv = *reinterpret_cast<const unsigned*>(h2 + (s << 6) + l32 * 2);
    acc0 = fmaf(ex, bf2f((u16)(hv & 0xffffu)), acc0);
    acc1 = fmaf(ex, bf2f((u16)(hv >> 16)), acc1);
  }
  float inv = 1.f / (den + 1e-16f);
  float2 o;
  o.x = acc0 * inv + b2[l32 * 2];
  o.y = acc1 * inv + b2[l32 * 2 + 1];
  *reinterpret_cast<float2*>(out + (((size_t)node) << 6) + l32 * 2) = o;
}

// ---------------- launch ----------------
extern "C" void kernel_launch(void* const* d_in, const int* in_sizes, int n_in,
                              void* d_out, int out_size, void* d_ws, size_t ws_size,
                              hipStream_t stream) {
  const float* x   = (const float*)d_in[0];
  const int*   ei  = (const int*)d_in[1];
  const float* W1  = (const float*)d_in[3];
  const float* a1s = (const float*)d_in[4];
  const float* a1d = (const float*)d_in[5];
  const float* b1  = (const float*)d_in[6];
  const float* W2  = (const float*)d_in[7];
  const float* a2s = (const float*)d_in[8];
  const float* a2d = (const float*)d_in[9];
  const float* b2  = (const float*)d_in[10];
  float* out = (float*)d_out;

  const int IN_DIM = 256, H1D1 = 512, D2 = 64;
  const int N = in_sizes[0] / IN_DIM;
  const int E = in_sizes[1] / 2;

  char* ws = (char*)d_ws;
  size_t off = 0;
  auto alloc = [&](size_t bytes) -> void* {
    void* p = ws + off;
    off += (bytes + 255) & ~(size_t)255;
    return p;
  };
  u16*  w1t    = (u16*)alloc((size_t)H1D1 * IN_DIM * 2);
  u16*  w2t    = (u16*)alloc((size_t)D2 * H1D1 * 2);
  u16*  h1b    = (u16*)alloc((size_t)N * H1D1 * 2);
  int*  cnt    = (int*)alloc((size_t)N * 4);
  float* as1   = (float*)alloc((size_t)N * 4 * 4);
  float* ad1   = (float*)alloc((size_t)N * 4 * 4);
  float* as2   = (float*)alloc((size_t)N * 4);
  float* ad2   = (float*)alloc((size_t)N * 4);
  int*  cursor = (int*)alloc((size_t)N * 4);
  int*  rowoff = (int*)alloc((size_t)(N + 1) * 4);
  int*  bsum   = (int*)alloc(256 * 4);
  int*  csr    = (int*)alloc((size_t)(E + N) * 4);
  u16*  h1o    = (u16*)alloc((size_t)N * H1D1 * 2);
  u16*  h2b    = (u16*)alloc((size_t)N * D2 * 2);
  (void)n_in; (void)out_size; (void)ws_size;

  const int* esrc = ei;
  const int* edst = ei + E;

  (void)hipMemsetAsync(cnt, 0, (size_t)N * 4, stream);

  int eb = (E + 255) / 256;
  prep_kernel<<<640 + eb, 256, 0, stream>>>(W1, W2, edst, w1t, w2t, cnt, E);

  // gemm1: BM=128, NP=4 col-panels, XCD-grouped padded grid (R15 config)
  const int NRB = (N + 127) / 128;
  const int g1 = ((NRB + 7) / 8) * 8 * 4;
  gemm1_alpha_kernel<128, 128, 4, 256, 64, 4, 4, 128><<<g1, 256, 0, stream>>>(
      x, w1t, h1b, a1s, a1d, as1, ad1, N);

  int nsb = (N + 255) / 256;
  scan_a_kernel<<<nsb, 256, 0, stream>>>(cnt, bsum, N);
  scan_c_kernel<<<nsb, 256, 0, stream>>>(cnt, bsum, rowoff, cursor, N);
  scatter_kernel<<<(E + N + 255) / 256, 256, 0, stream>>>(esrc, edst, cursor, csr, E, N);

  agg1_kernel<<<(N + 3) / 4, 256, 0, stream>>>(h1b, as1, ad1, rowoff, csr, b1, h1o, N);

  dim3 g2((N + 63) / 64, 1);
  gemm_alpha_kernel<64, 64, 4, 512, 64, 1, 64><<<g2, 256, 0, stream>>>(
      h1o, w2t, h2b, a2s, a2d, as2, ad2, N, D2);

  agg2_kernel<<<((size_t)N * 32 + 255) / 256, 256, 0, stream>>>(h2b, as2, ad2, rowoff, csr, b2, out, N);
}

// Round 19
// 219.550 us; speedup vs baseline: 1.0534x; 1.0139x over previous
//
#include <hip/hip_runtime.h>
#include <cstdint>

typedef unsigned short u16;
typedef short bf16x8_t __attribute__((ext_vector_type(8)));
typedef float f32x4_t __attribute__((ext_vector_type(4)));

#define DEVFN __device__ __forceinline__

DEVFN u16 f2bf(float f) {
  unsigned u = __builtin_bit_cast(unsigned, f);
  u = (u + 0x7fffu + ((u >> 16) & 1u)) >> 16;
  return (u16)u;
}
DEVFN float bf2f(u16 s) {
  unsigned u = ((unsigned)s) << 16;
  return __builtin_bit_cast(float, u);
}
DEVFN unsigned pk2bf(float a, float b) {
  return (unsigned)f2bf(a) | ((unsigned)f2bf(b) << 16);
}

// global -> LDS direct copy, 16B per lane; LDS dest linear in lane order.
DEVFN void gload_lds16(const u16* g, u16* l) {
  __builtin_amdgcn_global_load_lds(
      (const __attribute__((address_space(1))) void*)g,
      (__attribute__((address_space(3))) void*)l, 16, 0, 0);
}

// ---------------- prep: W1/W2 transpose->bf16, deg histogram ----------------
__global__ void prep_kernel(const float* __restrict__ W1, const float* __restrict__ W2,
                            const int* __restrict__ edst,
                            u16* __restrict__ w1t, u16* __restrict__ w2t,
                            int* __restrict__ cnt, int e) {
  int b = blockIdx.x;
  if (b < 512) {                         // W1 [256][512] -> w1t [512][256]
    int idx = b * 256 + threadIdx.x;
    int k = idx >> 9, m = idx & 511;
    w1t[m * 256 + k] = f2bf(W1[idx]);
  } else if (b < 640) {                  // W2 [512][64] -> w2t [64][512]
    int idx = (b - 512) * 256 + threadIdx.x;
    int k = idx >> 6, m = idx & 63;
    w2t[m * 512 + k] = f2bf(W2[idx]);
  } else {                               // deg histogram
    int i = (b - 640) * 256 + threadIdx.x;
    if (i < e) atomicAdd(&cnt[edst[i]], 1);
  }
}

// ================= GEMM1 (R15 config): f32 A fused convert, swizzled, XCD-grouped
// A[M][K] f32 @ BT[NP*BN][K] bf16 -> C[M][NP*BN] bf16 + fused alpha dots.
// The NP col-panel blocks sharing one A row-block get the same bid%8 (same XCD
// under round-robin dispatch) -> A panel fetched into that XCD's L2 once.
// T2 swizzle (BK=64, 128B rows): A reg-staged with swizzled ds_write slot;
// B gload_lds with pre-swizzled source column; reads XOR the same pattern.
template<int BM, int BN, int WROWS, int K, int BK, int NP, int H, int DH>
__global__ __launch_bounds__(256) void gemm1_alpha_kernel(
    const float* __restrict__ A, const u16* __restrict__ BT, u16* __restrict__ C,
    const float* __restrict__ a_s, const float* __restrict__ a_d,
    float* __restrict__ as_out, float* __restrict__ ad_out, int M)
{
  constexpr int N = NP * BN;
  constexpr int WM = BM / WROWS;
  constexpr int MF = WM / 16;
  constexpr int NF = BN / 16;
  constexpr int KK = BK / 32;
  static_assert(BK == 64, "swizzle derived for 128B rows");
  __shared__ __align__(16) u16 sA[BM][BK];
  __shared__ __align__(16) u16 sB[BN][BK];

  const int tid = threadIdx.x;
  const int lane = tid & 63;
  const int wr = tid >> 6;

  const int bid = blockIdx.x;
  const int xcd = bid & 7;
  const int rest = bid >> 3;
  const int p = rest & (NP - 1);
  const int rb = rest / NP;
  const int r = rb * 8 + xcd;
  const int NRB = (M + BM - 1) / BM;
  if (r >= NRB) return;
  const int brow = r * BM;
  const int bcol = p * BN;

  f32x4_t acc[MF][NF];
#pragma unroll
  for (int i = 0; i < MF; ++i)
#pragma unroll
    for (int j = 0; j < NF; ++j) acc[i][j] = f32x4_t{0.f, 0.f, 0.f, 0.f};

  const int rsel = lane & 15;
  const int kgrp = (lane >> 4) * 8;
  const int rx = (rsel & 7) * 8;       // read-side XOR (u16 units)

#pragma unroll
  for (int k0 = 0; k0 < K; k0 += BK) {
    // stage A: f32 global -> regs -> bf16 pack -> swizzled ds_write_b128
    constexpr int RA = BM * BK / 2048;   // 4 rounds
#pragma unroll
    for (int c = 0; c < RA; ++c) {
      int t = c * 256 + tid;
      int row = t >> 3;
      int gr = brow + row; gr = gr < M ? gr : M - 1;
      const float* src = A + (size_t)gr * K + k0 + (t & 7) * 8;
      float4 v0 = *reinterpret_cast<const float4*>(src);
      float4 v1 = *reinterpret_cast<const float4*>(src + 4);
      uint4 pk;
      pk.x = pk2bf(v0.x, v0.y);
      pk.y = pk2bf(v0.z, v0.w);
      pk.z = pk2bf(v1.x, v1.y);
      pk.w = pk2bf(v1.z, v1.w);
      int slot = (t & 7) ^ (row & 7);
      *reinterpret_cast<uint4*>(&sA[0][0] + row * BK + slot * 8) = pk;
    }
    // stage B via global_load_lds with pre-swizzled source column (L2-hot)
    constexpr int RB = BN * BK / 2048;
#pragma unroll
    for (int c = 0; c < RB; ++c) {
      int t = c * 256 + tid;
      int row = t >> 3;
      int col = ((t & 7) ^ (row & 7)) * 8;
      gload_lds16(BT + (size_t)(bcol + row) * K + k0 + col, &sB[0][0] + t * 8);
    }
    __syncthreads();
#pragma unroll
    for (int kk = 0; kk < KK; ++kk) {
      const int cswz = (kk * 32 + kgrp) ^ rx;
      bf16x8_t af[MF], bfr[NF];
#pragma unroll
      for (int i = 0; i < MF; ++i) {
        int row = wr * WM + i * 16 + rsel;
        af[i] = *reinterpret_cast<const bf16x8_t*>(&sA[0][0] + row * BK + cswz);
      }
#pragma unroll
      for (int j = 0; j < NF; ++j) {
        int row = j * 16 + rsel;
        bfr[j] = *reinterpret_cast<const bf16x8_t*>(&sB[0][0] + row * BK + cswz);
      }
#pragma unroll
      for (int i = 0; i < MF; ++i)
#pragma unroll
        for (int j = 0; j < NF; ++j)
          acc[i][j] = __builtin_amdgcn_mfma_f32_16x16x32_bf16(af[i], bfr[j], acc[i][j], 0, 0, 0);
    }
    __syncthreads();
  }

  const int crow0 = (lane >> 4) * 4;
  const int ccol = lane & 15;

  // C write
#pragma unroll
  for (int i = 0; i < MF; ++i)
#pragma unroll
    for (int j = 0; j < NF; ++j)
#pragma unroll
      for (int rr = 0; rr < 4; ++rr) {
        int gr = brow + wr * WM + i * 16 + crow0 + rr;
        int gc = bcol + j * 16 + ccol;
        if (gr < M) C[(size_t)gr * N + gc] = f2bf(acc[i][j][rr]);
      }

  // fused alpha dots (1 wave owns a row; BN==DH so one block owns (row, head))
  const int head = bcol / DH;
  float asv[NF], adv[NF];
#pragma unroll
  for (int j = 0; j < NF; ++j) {
    int gc = bcol + j * 16 + ccol;
    asv[j] = a_s[gc];
    adv[j] = a_d[gc];
  }
#pragma unroll
  for (int i = 0; i < MF; ++i) {
#pragma unroll
    for (int rr = 0; rr < 4; ++rr) {
      float ps = 0.f, pd = 0.f;
#pragma unroll
      for (int j = 0; j < NF; ++j) {
        float v = acc[i][j][rr];
        ps = fmaf(v, asv[j], ps);
        pd = fmaf(v, adv[j], pd);
      }
#pragma unroll
      for (int d = 1; d < 16; d <<= 1) {
        ps += __shfl_xor(ps, d, 64);
        pd += __shfl_xor(pd, d, 64);
      }
      if ((lane & 15) == 0) {
        int gr = brow + wr * WM + i * 16 + crow0 + rr;
        if (gr < M) {
          as_out[(size_t)gr * H + head] = ps;
          ad_out[(size_t)gr * H + head] = pd;
        }
      }
    }
  }
}

// ---------------- GEMM2 (R15 config: swizzled gload_lds A+B) + fused alpha2 ----
template<int BM, int BN, int WROWS, int K, int BK, int H, int DH>
__global__ __launch_bounds__(256) void gemm_alpha_kernel(
    const u16* __restrict__ A, const u16* __restrict__ BT, u16* __restrict__ C,
    const float* __restrict__ a_s, const float* __restrict__ a_d,
    float* __restrict__ as_out, float* __restrict__ ad_out, int M, int N)
{
  static_assert(BN == DH, "alpha store ownership");
  static_assert(BK == 64, "swizzle derived for 128B rows");
  constexpr int WM = BM / WROWS;
  constexpr int MF = WM / 16;
  constexpr int NF = BN / 16;
  constexpr int KK = BK / 32;
  __shared__ __align__(16) u16 sA[BM][BK];
  __shared__ __align__(16) u16 sB[BN][BK];

  const int tid = threadIdx.x;
  const int lane = tid & 63;
  const int wr = tid >> 6;
  const int brow = blockIdx.x * BM;
  const int bcol = blockIdx.y * BN;

  f32x4_t acc[MF][NF];
#pragma unroll
  for (int i = 0; i < MF; ++i)
#pragma unroll
    for (int j = 0; j < NF; ++j) acc[i][j] = f32x4_t{0.f, 0.f, 0.f, 0.f};

  const int rsel = lane & 15;
  const int kgrp = (lane >> 4) * 8;
  const int rx = (rsel & 7) * 8;

#pragma unroll
  for (int k0 = 0; k0 < K; k0 += BK) {
    constexpr int RA = BM * BK / 2048;
#pragma unroll
    for (int c = 0; c < RA; ++c) {
      int t = c * 256 + tid;
      int row = t >> 3;
      int col = ((t & 7) ^ (row & 7)) * 8;
      int gr = brow + row; gr = gr < M ? gr : M - 1;
      gload_lds16(A + (size_t)gr * K + k0 + col, &sA[0][0] + t * 8);
    }
    constexpr int RB = BN * BK / 2048;
#pragma unroll
    for (int c = 0; c < RB; ++c) {
      int t = c * 256 + tid;
      int row = t >> 3;
      int col = ((t & 7) ^ (row & 7)) * 8;
      gload_lds16(BT + (size_t)(bcol + row) * K + k0 + col, &sB[0][0] + t * 8);
    }
    __syncthreads();
#pragma unroll
    for (int kk = 0; kk < KK; ++kk) {
      const int cswz = (kk * 32 + kgrp) ^ rx;
      bf16x8_t af[MF], bfr[NF];
#pragma unroll
      for (int i = 0; i < MF; ++i) {
        int row = wr * WM + i * 16 + rsel;
        af[i] = *reinterpret_cast<const bf16x8_t*>(&sA[0][0] + row * BK + cswz);
      }
#pragma unroll
      for (int j = 0; j < NF; ++j) {
        int row = j * 16 + rsel;
        bfr[j] = *reinterpret_cast<const bf16x8_t*>(&sB[0][0] + row * BK + cswz);
      }
#pragma unroll
      for (int i = 0; i < MF; ++i)
#pragma unroll
        for (int j = 0; j < NF; ++j)
          acc[i][j] = __builtin_amdgcn_mfma_f32_16x16x32_bf16(af[i], bfr[j], acc[i][j], 0, 0, 0);
    }
    __syncthreads();
  }

  const int crow0 = (lane >> 4) * 4;
  const int ccol = lane & 15;

#pragma unroll
  for (int i = 0; i < MF; ++i)
#pragma unroll
    for (int j = 0; j < NF; ++j)
#pragma unroll
      for (int rr = 0; rr < 4; ++rr) {
        int gr = brow + wr * WM + i * 16 + crow0 + rr;
        int gc = bcol + j * 16 + ccol;
        if (gr < M) C[(size_t)gr * N + gc] = f2bf(acc[i][j][rr]);
      }

  const int head = bcol / DH;
  float asv[NF], adv[NF];
#pragma unroll
  for (int j = 0; j < NF; ++j) {
    int gc = bcol + j * 16 + ccol;
    asv[j] = a_s[gc];
    adv[j] = a_d[gc];
  }
#pragma unroll
  for (int i = 0; i < MF; ++i) {
#pragma unroll
    for (int rr = 0; rr < 4; ++rr) {
      float ps = 0.f, pd = 0.f;
#pragma unroll
      for (int j = 0; j < NF; ++j) {
        float v = acc[i][j][rr];
        ps = fmaf(v, asv[j], ps);
        pd = fmaf(v, adv[j], pd);
      }
#pragma unroll
      for (int d = 1; d < 16; d <<= 1) {
        ps += __shfl_xor(ps, d, 64);
        pd += __shfl_xor(pd, d, 64);
      }
      if ((lane & 15) == 0) {
        int gr = brow + wr * WM + i * 16 + crow0 + rr;
        if (gr < M) {
          as_out[(size_t)gr * H + head] = ps;
          ad_out[(size_t)gr * H + head] = pd;
        }
      }
    }
  }
}

// ---------------- CSR build ----------------
DEVFN int block_scan_256(int v, int tid, int* wsum) {
#pragma unroll
  for (int d = 1; d < 64; d <<= 1) {
    int u = __shfl_up(v, d, 64);
    if ((tid & 63) >= d) v += u;
  }
  if ((tid & 63) == 63) wsum[tid >> 6] = v;
  __syncthreads();
  int add = 0;
#pragma unroll
  for (int w = 0; w < 4; ++w) add += (w < (tid >> 6)) ? wsum[w] : 0;
  __syncthreads();
  return v + add;
}

__global__ __launch_bounds__(256) void scan_a_kernel(const int* __restrict__ cnt, int* __restrict__ bsum, int n) {
  __shared__ int ws4[4];
  int i = blockIdx.x * 256 + threadIdx.x;
  int v = (i < n) ? cnt[i] + 1 : 0;   // +1 self loop
  int incl = block_scan_256(v, threadIdx.x, ws4);
  if (threadIdx.x == 255) bsum[blockIdx.x] = incl;
}

__global__ __launch_bounds__(256) void scan_c_kernel(
    const int* __restrict__ cnt, const int* __restrict__ bsum,
    int* __restrict__ rowoff, int* __restrict__ cursor, int n)
{
  __shared__ int ws4[4];
  __shared__ int ws4b[4];
  __shared__ int base_sh;
  int pre = 0;
  for (int w = threadIdx.x; w < blockIdx.x; w += 256) pre += bsum[w];
#pragma unroll
  for (int d = 1; d < 64; d <<= 1) pre += __shfl_xor(pre, d, 64);
  if ((threadIdx.x & 63) == 0) ws4b[threadIdx.x >> 6] = pre;
  __syncthreads();
  if (threadIdx.x == 0) base_sh = ws4b[0] + ws4b[1] + ws4b[2] + ws4b[3];
  int i = blockIdx.x * 256 + threadIdx.x;
  int v = (i < n) ? cnt[i] + 1 : 0;
  int incl = block_scan_256(v, threadIdx.x, ws4);
  int off = base_sh + incl - v;
  if (i < n) {
    rowoff[i] = off;
    cursor[i] = off;
    if (i == n - 1) rowoff[n] = off + v;
  }
}

__global__ void scatter_kernel(const int* __restrict__ srcs, const int* __restrict__ dsts,
                               int* __restrict__ cursor, int* __restrict__ csr, int e, int n) {
  int i = blockIdx.x * 256 + threadIdx.x;
  if (i >= e + n) return;
  int s, d;
  if (i < e) { s = srcs[i]; d = dsts[i]; }
  else       { s = i - e; d = s; }
  int pos = atomicAdd(&cursor[d], 1);
  csr[pos] = s;
}

// ---------------- agg1: gather h1b, fused softmax (no-max-shift), b1+ELU -------
__global__ __launch_bounds__(256) void agg1_kernel(
    const u16* __restrict__ h1, const float* __restrict__ as1,
    const float* __restrict__ ad1, const int* __restrict__ rowoff,
    const int* __restrict__ csr, const float* __restrict__ b1,
    u16* __restrict__ out, int n)
{
  int node = (blockIdx.x * 256 + threadIdx.x) >> 6;
  int lane = threadIdx.x & 63;
  if (node >= n) return;
  const unsigned head = lane >> 4;
  const unsigned dimbase = lane * 8;
  int e0 = rowoff[node], e1 = rowoff[node + 1];
  float advn = ad1[((unsigned)node << 2) + head];

  float acc[8];
#pragma unroll
  for (int j = 0; j < 8; ++j) acc[j] = 0.f;
  float den = 0.f;

  for (int e = e0; e < e1; ++e) {
    unsigned s = (unsigned)csr[e];
    float t = as1[(s << 2) + head] + advn;
    float l = fmaxf(t, 0.2f * t);          // leaky_relu, branchless
    float ex = __expf(l);
    den += ex;
    bf16x8_t hv = *reinterpret_cast<const bf16x8_t*>(h1 + ((s << 9) + dimbase));
#pragma unroll
    for (int j = 0; j < 8; ++j) acc[j] = fmaf(ex, bf2f((u16)hv[j]), acc[j]);
  }

  float inv = 1.f / (den + 1e-16f);
  u16* orow = out + (((unsigned)node << 9) + dimbase);
#pragma unroll
  for (int j = 0; j < 8; ++j) {
    float v = acc[j] * inv + b1[dimbase + j];
    v = v > 0.f ? v : (__expf(v) - 1.0f);   // ELU (abs err ~1e-7 << bf16 eps)
    orow[j] = f2bf(v);
  }
}

// ---------------- agg2: half-wave per node, fused softmax ----------------
__global__ __launch_bounds__(256) void agg2_kernel(
    const u16* __restrict__ h2, const float* __restrict__ as2,
    const float* __restrict__ ad2, const int* __restrict__ rowoff,
    const int* __restrict__ csr, const float* __restrict__ b2,
    float* __restrict__ out, int n)
{
  int node = (blockIdx.x * 256 + threadIdx.x) >> 5;
  int l32 = threadIdx.x & 31;
  if (node >= n) return;
  int e0 = rowoff[node], e1 = rowoff[node + 1];
  float advn = ad2[node];

  float acc0 = 0.f, acc1 = 0.f, den = 0.f;
  for (int e = e0; e < e1; ++e) {
    unsigned s = (unsigned)csr[e];
    float t = as2[s] + advn;
    float l = fmaxf(t, 0.2f * t);
    float ex = __expf(l);
    den += ex;
    unsigned hv = *reinterpret_cast<const unsigned*>(h2 + (s << 6) + l32 * 2);
    acc0 = fmaf(ex, bf2f((u16)(hv & 0xffffu)), acc0);
    acc1 = fmaf(ex, bf2f((u16)(hv >> 16)), acc1);
  }
  float inv = 1.f / (den + 1e-16f);
  float2 o;
  o.x = acc0 * inv + b2[l32 * 2];
  o.y = acc1 * inv + b2[l32 * 2 + 1];
  *reinterpret_cast<float2*>(out + (((size_t)node) << 6) + l32 * 2) = o;
}

// ---------------- launch ----------------
extern "C" void kernel_launch(void* const* d_in, const int* in_sizes, int n_in,
                              void* d_out, int out_size, void* d_ws, size_t ws_size,
                              hipStream_t stream) {
  const float* x   = (const float*)d_in[0];
  const int*   ei  = (const int*)d_in[1];
  const float* W1  = (const float*)d_in[3];
  const float* a1s = (const float*)d_in[4];
  const float* a1d = (const float*)d_in[5];
  const float* b1  = (const float*)d_in[6];
  const float* W2  = (const float*)d_in[7];
  const float* a2s = (const float*)d_in[8];
  const float* a2d = (const float*)d_in[9];
  const float* b2  = (const float*)d_in[10];
  float* out = (float*)d_out;

  const int IN_DIM = 256, H1D1 = 512, D2 = 64;
  const int N = in_sizes[0] / IN_DIM;
  const int E = in_sizes[1] / 2;

  char* ws = (char*)d_ws;
  size_t off = 0;
  auto alloc = [&](size_t bytes) -> void* {
    void* p = ws + off;
    off += (bytes + 255) & ~(size_t)255;
    return p;
  };
  u16*  w1t    = (u16*)alloc((size_t)H1D1 * IN_DIM * 2);
  u16*  w2t    = (u16*)alloc((size_t)D2 * H1D1 * 2);
  u16*  h1b    = (u16*)alloc((size_t)N * H1D1 * 2);
  int*  cnt    = (int*)alloc((size_t)N * 4);
  float* as1   = (float*)alloc((size_t)N * 4 * 4);
  float* ad1   = (float*)alloc((size_t)N * 4 * 4);
  float* as2   = (float*)alloc((size_t)N * 4);
  float* ad2   = (float*)alloc((size_t)N * 4);
  int*  cursor = (int*)alloc((size_t)N * 4);
  int*  rowoff = (int*)alloc((size_t)(N + 1) * 4);
  int*  bsum   = (int*)alloc(256 * 4);
  int*  csr    = (int*)alloc((size_t)(E + N) * 4);
  u16*  h1o    = (u16*)alloc((size_t)N * H1D1 * 2);
  u16*  h2b    = (u16*)alloc((size_t)N * D2 * 2);
  (void)n_in; (void)out_size; (void)ws_size;

  const int* esrc = ei;
  const int* edst = ei + E;

  (void)hipMemsetAsync(cnt, 0, (size_t)N * 4, stream);

  int eb = (E + 255) / 256;
  prep_kernel<<<640 + eb, 256, 0, stream>>>(W1, W2, edst, w1t, w2t, cnt, E);

  // gemm1: BM=128, NP=4 col-panels, XCD-grouped padded grid (R15 config)
  const int NRB = (N + 127) / 128;
  const int g1 = ((NRB + 7) / 8) * 8 * 4;
  gemm1_alpha_kernel<128, 128, 4, 256, 64, 4, 4, 128><<<g1, 256, 0, stream>>>(
      x, w1t, h1b, a1s, a1d, as1, ad1, N);

  int nsb = (N + 255) / 256;
  scan_a_kernel<<<nsb, 256, 0, stream>>>(cnt, bsum, N);
  scan_c_kernel<<<nsb, 256, 0, stream>>>(cnt, bsum, rowoff, cursor, N);
  scatter_kernel<<<(E + N + 255) / 256, 256, 0, stream>>>(esrc, edst, cursor, csr, E, N);

  agg1_kernel<<<(N + 3) / 4, 256, 0, stream>>>(h1b, as1, ad1, rowoff, csr, b1, h1o, N);

  dim3 g2((N + 63) / 64, 1);
  gemm_alpha_kernel<64, 64, 4, 512, 64, 1, 64><<<g2, 256, 0, stream>>>(
      h1o, w2t, h2b, a2s, a2d, as2, ad2, N, D2);

  agg2_kernel<<<((size_t)N * 32 + 255) / 256, 256, 0, stream>>>(h2b, as2, ad2, rowoff, csr, b2, out, N);
}